// Round 1
// baseline (95.803 us; speedup 1.0000x reference)
//
#include <hip/hip_runtime.h>

#define Bn 32
#define Cn 256
#define HWn 3136          // 56*56
#define HW4 784           // HWn/4
#define NTHREADS 256

// ---------------------------------------------------------------------------
// K1: per-(b,c) plane reduction: cim = mean(x*cgrad), dim = mean(x*dgrad)
// ---------------------------------------------------------------------------
__global__ __launch_bounds__(NTHREADS) void importance_kernel(
    const float* __restrict__ x, const float* __restrict__ cg,
    const float* __restrict__ dg, float* __restrict__ cim,
    float* __restrict__ dimv) {
  const int bc = blockIdx.x;
  const size_t base = (size_t)bc * HWn;
  const float4* __restrict__ xp = (const float4*)(x + base);
  const float4* __restrict__ cp = (const float4*)(cg + base);
  const float4* __restrict__ dp = (const float4*)(dg + base);

  float accC = 0.f, accD = 0.f;
  for (int i = threadIdx.x; i < HW4; i += NTHREADS) {
    float4 xv = xp[i];
    float4 cv = cp[i];
    float4 dv = dp[i];
    accC += xv.x * cv.x + xv.y * cv.y + xv.z * cv.z + xv.w * cv.w;
    accD += xv.x * dv.x + xv.y * dv.y + xv.z * dv.z + xv.w * dv.w;
  }
  // wave (64-lane) reduce
  for (int off = 32; off > 0; off >>= 1) {
    accC += __shfl_down(accC, off);
    accD += __shfl_down(accD, off);
  }
  __shared__ float rc[4], rd[4];
  const int wave = threadIdx.x >> 6;
  const int lane = threadIdx.x & 63;
  if (lane == 0) { rc[wave] = accC; rd[wave] = accD; }
  __syncthreads();
  if (threadIdx.x == 0) {
    float sC = rc[0] + rc[1] + rc[2] + rc[3];
    float sD = rd[0] + rd[1] + rd[2] + rd[3];
    cim[bc] = sC * (1.0f / HWn);
    dimv[bc] = sD * (1.0f / HWn);
  }
}

// ---------------------------------------------------------------------------
// K2: per-sample quantile thresholds (rank selection over 256 channels) and
// mask generation: m1 = cs&ds, m2 = (!cs)&ds, mdi = !ds
// quantile(0.5): pos = 127.5 -> 0.5*(s127+s128)
// quantile(0.8): pos = 0.8*255 = 204.0 -> s204
// ---------------------------------------------------------------------------
__global__ __launch_bounds__(NTHREADS) void quantile_mask_kernel(
    const float* __restrict__ cim, const float* __restrict__ dimv,
    float* __restrict__ m1, float* __restrict__ m2, float* __restrict__ mdi) {
  const int b = blockIdx.x;
  const int c = threadIdx.x;
  __shared__ float sc[Cn], sd[Cn];
  __shared__ float q127, q128, q204;
  const float v = cim[b * Cn + c];
  const float w = dimv[b * Cn + c];
  sc[c] = v;
  sd[c] = w;
  __syncthreads();

  int cl = 0, ce = 0, dl = 0, de = 0;
  for (int j = 0; j < Cn; ++j) {
    float u = sc[j];
    cl += (u < v);
    ce += (u == v);
    float t = sd[j];
    dl += (t < w);
    de += (t == w);
  }
  if (cl <= 127 && 127 < cl + ce) q127 = v;
  if (cl <= 128 && 128 < cl + ce) q128 = v;
  if (dl <= 204 && 204 < dl + de) q204 = w;
  __syncthreads();

  const float cthr = 0.5f * (q127 + q128);
  const float dthr = q204;
  const bool cs = v > cthr;
  const bool ds = w > dthr;
  m1[b * Cn + c] = (cs && ds) ? 1.f : 0.f;
  m2[b * Cn + c] = (!cs && ds) ? 1.f : 0.f;
  mdi[b * Cn + c] = ds ? 0.f : 1.f;
}

// ---------------------------------------------------------------------------
// K3: out[b,c,:] = A*x[b,c,:] + B1*x[sb,c,:] + B2*x[db,c,:]
//   A  = mdi[b,c] + s0*m1[b,c] + s1*m2[b,c]
//   B1 = (1-s0)*m1[sb,c]
//   B2 = (1-s1)*m2[db,c]
// ---------------------------------------------------------------------------
__global__ __launch_bounds__(NTHREADS) void mix_kernel(
    const float* __restrict__ x, const float* __restrict__ ms,
    const int* __restrict__ same_idx, const int* __restrict__ diff_idx,
    const float* __restrict__ m1, const float* __restrict__ m2,
    const float* __restrict__ mdi, float* __restrict__ out) {
  const int bc = blockIdx.x;
  const int b = bc >> 8;
  const int c = bc & 255;
  const int sb = same_idx[b];
  const int db = diff_idx[b];
  const float s0 = ms[b * 2 + 0];
  const float s1 = ms[b * 2 + 1];

  const float A = mdi[bc] + s0 * m1[bc] + s1 * m2[bc];
  const float B1 = (1.f - s0) * m1[sb * Cn + c];
  const float B2 = (1.f - s1) * m2[db * Cn + c];

  const float4* __restrict__ xp = (const float4*)(x + (size_t)bc * HWn);
  const float4* __restrict__ xs = (const float4*)(x + ((size_t)sb * Cn + c) * HWn);
  const float4* __restrict__ xd = (const float4*)(x + ((size_t)db * Cn + c) * HWn);
  float4* __restrict__ op = (float4*)(out + (size_t)bc * HWn);

  const bool u1 = (B1 != 0.f);
  const bool u2 = (B2 != 0.f);

  for (int i = threadIdx.x; i < HW4; i += NTHREADS) {
    float4 xv = xp[i];
    float4 r;
    r.x = A * xv.x;
    r.y = A * xv.y;
    r.z = A * xv.z;
    r.w = A * xv.w;
    if (u1) {
      float4 sv = xs[i];
      r.x += B1 * sv.x;
      r.y += B1 * sv.y;
      r.z += B1 * sv.z;
      r.w += B1 * sv.w;
    }
    if (u2) {
      float4 dv = xd[i];
      r.x += B2 * dv.x;
      r.y += B2 * dv.y;
      r.z += B2 * dv.z;
      r.w += B2 * dv.w;
    }
    op[i] = r;
  }
}

extern "C" void kernel_launch(void* const* d_in, const int* in_sizes, int n_in,
                              void* d_out, int out_size, void* d_ws, size_t ws_size,
                              hipStream_t stream) {
  const float* x  = (const float*)d_in[0];
  const float* cg = (const float*)d_in[1];
  const float* dg = (const float*)d_in[2];
  const float* ms = (const float*)d_in[3];
  // d_in[4] = y, d_in[5] = domain (unused: index pickers precomputed)
  const int* same_idx = (const int*)d_in[6];
  const int* diff_idx = (const int*)d_in[7];
  float* out = (float*)d_out;

  float* ws = (float*)d_ws;
  float* cim  = ws;                // B*C
  float* dimv = ws + Bn * Cn;      // B*C
  float* m1   = ws + 2 * Bn * Cn;  // B*C
  float* m2   = ws + 3 * Bn * Cn;  // B*C
  float* mdi  = ws + 4 * Bn * Cn;  // B*C

  importance_kernel<<<Bn * Cn, NTHREADS, 0, stream>>>(x, cg, dg, cim, dimv);
  quantile_mask_kernel<<<Bn, NTHREADS, 0, stream>>>(cim, dimv, m1, m2, mdi);
  mix_kernel<<<Bn * Cn, NTHREADS, 0, stream>>>(x, ms, same_idx, diff_idx, m1, m2, mdi, out);
}

// Round 3
// 88.664 us; speedup vs baseline: 1.0805x; 1.0805x over previous
//
#include <hip/hip_runtime.h>

#define Bn 32
#define Cn 256
#define HWn 3136          // 56*56
#define HW4 784           // HWn/4  = 3*256 + 16
#define NTHREADS 256

typedef float f4 __attribute__((ext_vector_type(4)));

__device__ __forceinline__ float dot4(f4 a, f4 b) {
  return a.x * b.x + a.y * b.y + a.z * b.z + a.w * b.w;
}

// ---------------------------------------------------------------------------
// K1: per-(b,c) plane reduction: cim = mean(x*cgrad), dim = mean(x*dgrad)
// Fully unrolled: 9 independent float4 loads issued before any use (MLP).
// cg/dg are single-use -> nontemporal loads (keep x resident in L3 for K3).
// ---------------------------------------------------------------------------
__global__ __launch_bounds__(NTHREADS) void importance_kernel(
    const float* __restrict__ x, const float* __restrict__ cg,
    const float* __restrict__ dg, float* __restrict__ cim,
    float* __restrict__ dimv) {
  const int bc = blockIdx.x;
  const size_t base = (size_t)bc * HWn;
  const f4* __restrict__ xp = (const f4*)(x + base);
  const f4* __restrict__ cp = (const f4*)(cg + base);
  const f4* __restrict__ dp = (const f4*)(dg + base);
  const int t = threadIdx.x;

  // main body: indices t, t+256, t+512  (covers 0..767)
  f4 xv0 = xp[t];
  f4 xv1 = xp[t + 256];
  f4 xv2 = xp[t + 512];
  f4 cv0 = __builtin_nontemporal_load(cp + t);
  f4 cv1 = __builtin_nontemporal_load(cp + t + 256);
  f4 cv2 = __builtin_nontemporal_load(cp + t + 512);
  f4 dv0 = __builtin_nontemporal_load(dp + t);
  f4 dv1 = __builtin_nontemporal_load(dp + t + 256);
  f4 dv2 = __builtin_nontemporal_load(dp + t + 512);

  float accC = dot4(xv0, cv0) + dot4(xv1, cv1) + dot4(xv2, cv2);
  float accD = dot4(xv0, dv0) + dot4(xv1, dv1) + dot4(xv2, dv2);

  // tail: indices 768..783 (16 float4), threads 0..15
  if (t < 16) {
    f4 xv3 = xp[768 + t];
    f4 cv3 = __builtin_nontemporal_load(cp + 768 + t);
    f4 dv3 = __builtin_nontemporal_load(dp + 768 + t);
    accC += dot4(xv3, cv3);
    accD += dot4(xv3, dv3);
  }

  // wave (64-lane) reduce
  for (int off = 32; off > 0; off >>= 1) {
    accC += __shfl_down(accC, off);
    accD += __shfl_down(accD, off);
  }
  __shared__ float rc[4], rd[4];
  const int wave = threadIdx.x >> 6;
  const int lane = threadIdx.x & 63;
  if (lane == 0) { rc[wave] = accC; rd[wave] = accD; }
  __syncthreads();
  if (threadIdx.x == 0) {
    float sC = rc[0] + rc[1] + rc[2] + rc[3];
    float sD = rd[0] + rd[1] + rd[2] + rd[3];
    cim[bc] = sC * (1.0f / HWn);
    dimv[bc] = sD * (1.0f / HWn);
  }
}

// ---------------------------------------------------------------------------
// K2: per-sample quantile thresholds (rank selection over 256 channels) and
// mask generation: m1 = cs&ds, m2 = (!cs)&ds, mdi = !ds
// quantile(0.5): pos = 127.5 -> 0.5*(s127+s128); quantile(0.8): pos=204 -> s204
// ---------------------------------------------------------------------------
__global__ __launch_bounds__(NTHREADS) void quantile_mask_kernel(
    const float* __restrict__ cim, const float* __restrict__ dimv,
    float* __restrict__ m1, float* __restrict__ m2, float* __restrict__ mdi) {
  const int b = blockIdx.x;
  const int c = threadIdx.x;
  __shared__ float sc[Cn], sd[Cn];
  __shared__ float q127, q128, q204;
  const float v = cim[b * Cn + c];
  const float w = dimv[b * Cn + c];
  sc[c] = v;
  sd[c] = w;
  __syncthreads();

  int cl = 0, ce = 0, dl = 0, de = 0;
  for (int j = 0; j < Cn; ++j) {
    float u = sc[j];
    cl += (u < v);
    ce += (u == v);
    float t = sd[j];
    dl += (t < w);
    de += (t == w);
  }
  if (cl <= 127 && 127 < cl + ce) q127 = v;
  if (cl <= 128 && 128 < cl + ce) q128 = v;
  if (dl <= 204 && 204 < dl + de) q204 = w;
  __syncthreads();

  const float cthr = 0.5f * (q127 + q128);
  const float dthr = q204;
  const bool cs = v > cthr;
  const bool ds = w > dthr;
  m1[b * Cn + c] = (cs && ds) ? 1.f : 0.f;
  m2[b * Cn + c] = (!cs && ds) ? 1.f : 0.f;
  mdi[b * Cn + c] = ds ? 0.f : 1.f;
}

// ---------------------------------------------------------------------------
// K3: out[b,c,:] = A*x[b,c,:] + B1*x[sb,c,:] + B2*x[db,c,:]
// Unrolled 3+tail like K1; out is never read back -> nontemporal stores
// (keeps x resident in L3 across graph replays).
// ---------------------------------------------------------------------------
__global__ __launch_bounds__(NTHREADS) void mix_kernel(
    const float* __restrict__ x, const float* __restrict__ ms,
    const int* __restrict__ same_idx, const int* __restrict__ diff_idx,
    const float* __restrict__ m1, const float* __restrict__ m2,
    const float* __restrict__ mdi, float* __restrict__ out) {
  const int bc = blockIdx.x;
  const int b = bc >> 8;
  const int c = bc & 255;
  const int sb = same_idx[b];
  const int db = diff_idx[b];
  const float s0 = ms[b * 2 + 0];
  const float s1 = ms[b * 2 + 1];

  const float A = mdi[bc] + s0 * m1[bc] + s1 * m2[bc];
  const float B1 = (1.f - s0) * m1[sb * Cn + c];
  const float B2 = (1.f - s1) * m2[db * Cn + c];

  const f4* __restrict__ xp = (const f4*)(x + (size_t)bc * HWn);
  const f4* __restrict__ xs = (const f4*)(x + ((size_t)sb * Cn + c) * HWn);
  const f4* __restrict__ xd = (const f4*)(x + ((size_t)db * Cn + c) * HWn);
  f4* __restrict__ op = (f4*)(out + (size_t)bc * HWn);

  const bool u1 = (B1 != 0.f);
  const bool u2 = (B2 != 0.f);
  const int t = threadIdx.x;

  f4 r0, r1, r2;
  {
    f4 xv0 = xp[t];
    f4 xv1 = xp[t + 256];
    f4 xv2 = xp[t + 512];
    r0 = A * xv0;
    r1 = A * xv1;
    r2 = A * xv2;
  }
  if (u1) {
    f4 s0v = xs[t];
    f4 s1v = xs[t + 256];
    f4 s2v = xs[t + 512];
    r0 += B1 * s0v;
    r1 += B1 * s1v;
    r2 += B1 * s2v;
  }
  if (u2) {
    f4 d0v = xd[t];
    f4 d1v = xd[t + 256];
    f4 d2v = xd[t + 512];
    r0 += B2 * d0v;
    r1 += B2 * d1v;
    r2 += B2 * d2v;
  }
  __builtin_nontemporal_store(r0, op + t);
  __builtin_nontemporal_store(r1, op + t + 256);
  __builtin_nontemporal_store(r2, op + t + 512);

  if (t < 16) {
    f4 xv3 = xp[768 + t];
    f4 r3 = A * xv3;
    if (u1) {
      f4 s3v = xs[768 + t];
      r3 += B1 * s3v;
    }
    if (u2) {
      f4 d3v = xd[768 + t];
      r3 += B2 * d3v;
    }
    __builtin_nontemporal_store(r3, op + 768 + t);
  }
}

extern "C" void kernel_launch(void* const* d_in, const int* in_sizes, int n_in,
                              void* d_out, int out_size, void* d_ws, size_t ws_size,
                              hipStream_t stream) {
  const float* x  = (const float*)d_in[0];
  const float* cg = (const float*)d_in[1];
  const float* dg = (const float*)d_in[2];
  const float* ms = (const float*)d_in[3];
  // d_in[4] = y, d_in[5] = domain (unused: index pickers precomputed)
  const int* same_idx = (const int*)d_in[6];
  const int* diff_idx = (const int*)d_in[7];
  float* out = (float*)d_out;

  float* ws = (float*)d_ws;
  float* cim  = ws;                // B*C
  float* dimv = ws + Bn * Cn;      // B*C
  float* m1   = ws + 2 * Bn * Cn;  // B*C
  float* m2   = ws + 3 * Bn * Cn;  // B*C
  float* mdi  = ws + 4 * Bn * Cn;  // B*C

  importance_kernel<<<Bn * Cn, NTHREADS, 0, stream>>>(x, cg, dg, cim, dimv);
  quantile_mask_kernel<<<Bn, NTHREADS, 0, stream>>>(cim, dimv, m1, m2, mdi);
  mix_kernel<<<Bn * Cn, NTHREADS, 0, stream>>>(x, ms, same_idx, diff_idx, m1, m2, mdi, out);
}